// Round 10
// baseline (220.807 us; speedup 1.0000x reference)
//
#include <hip/hip_runtime.h>
#include <stdint.h>

typedef unsigned short u16;
typedef uint32_t u32;
typedef __attribute__((ext_vector_type(8))) short short8;
typedef _Float16 half8 __attribute__((ext_vector_type(8)));
typedef __attribute__((ext_vector_type(4))) float f32x4;
typedef __attribute__((ext_vector_type(16))) float f32x16;

static constexpr int T_SEQ = 2048;
static constexpr int C_EMB = 768;
static constexpr int N_HD  = 12;
static constexpr int D_HD  = 64;
static constexpr int N_BH  = 48;   // B * H

#define MFMA32B(a, b, c) __builtin_amdgcn_mfma_f32_32x32x16_bf16((a), (b), (c), 0, 0, 0)

__device__ __forceinline__ f32x4 mfma16f(short8 a, short8 b, f32x4 c) {
  return __builtin_amdgcn_mfma_f32_16x16x32_f16(
      __builtin_bit_cast(half8, a), __builtin_bit_cast(half8, b), c, 0, 0, 0);
}
__device__ __forceinline__ f32x16 mfma32f(short8 a, short8 b, f32x16 c) {
  return __builtin_amdgcn_mfma_f32_32x32x16_f16(
      __builtin_bit_cast(half8, a), __builtin_bit_cast(half8, b), c, 0, 0, 0);
}

#if __has_builtin(__builtin_amdgcn_exp2f)
#define EXP2(x) __builtin_amdgcn_exp2f(x)
#else
#define EXP2(x) exp2f(x)
#endif

__device__ __forceinline__ u16 f2bf(float f) {
  union { float f; u32 u; } v; v.f = f;
  u32 r = v.u + 0x7FFFu + ((v.u >> 16) & 1u);   // RNE
  return (u16)(r >> 16);
}
__device__ __forceinline__ float bf2f(u16 h) {
  union { u32 u; float f; } v; v.u = ((u32)h) << 16; return v.f;
}
__device__ __forceinline__ u16 f2h(float f) {
  union { _Float16 h; u16 u; } v; v.h = (_Float16)f; return v.u;   // v_cvt_f16_f32 RNE
}
// pack two POSITIVE f32 -> u32 of 2 bf16 (low element = a), round-half-up. PROVEN (r6/7).
__device__ __forceinline__ u32 pack2bf(float a, float b) {
  union { float f; u32 u; } x, y; x.f = a; y.f = b;
  return __byte_perm(x.u + 0x8000u, y.u + 0x8000u, 0x7632);
}

__device__ __forceinline__ void gload_lds16(const void* g, void* l) {
  __builtin_amdgcn_global_load_lds((const __attribute__((address_space(1))) void*)g,
                                   (__attribute__((address_space(3))) void*)l, 16, 0, 0);
}

// XOR swizzle for [rows][64 elems of 2B] LDS tiles (128 B rows, 8 slots of 16 B)
__device__ __forceinline__ int swz(int r, int kb) {
  return r * 128 + (kb ^ ((r & 7) << 4));
}

// ---------------- fused fp32 -> f16 conversion of x, w_attn, w_proj ----------------
__global__ void cvt3_f16(const float* __restrict__ x, const float* __restrict__ wa,
                         const float* __restrict__ wp, u16* __restrict__ xf,
                         u16* __restrict__ waf, u16* __restrict__ wpf,
                         int n0, int n1, int n2) {
  int i = blockIdx.x * blockDim.x + threadIdx.x;
  int st = gridDim.x * blockDim.x;
  int ntot = n0 + n1 + n2;
  for (; i < ntot; i += st) {
    const float* s; u16* d; int j = i;
    if (j < n0) { s = x; d = xf; }
    else if (j < n0 + n1) { j -= n0; s = wa; d = waf; }
    else { j -= n0 + n1; s = wp; d = wpf; }
    float4 v = ((const float4*)s)[j];
    ushort4 o;
    o.x = f2h(v.x); o.y = f2h(v.y); o.z = f2h(v.z); o.w = f2h(v.w);
    ((ushort4*)d)[j] = o;
  }
}

// ---------------- NT GEMM, f16, 256x256 tile, BK=64, double-buffered ----------------
// Staging-traffic model (fits rounds 2/7/8/9): GEMM time ~ staged bytes / ~6 TB/s.
// 256x256 tile halves panel re-reads vs 128x128 (A re-read x9 not x18, B x32 not x64).
// 512 threads = 8 waves (2M x 4N), wave out 128x64, acc 8x4 f32x4, 1 block/CU.
// Same STAGE/swz/dbuf/barrier template as the verified 128x128 version.
// EPI 0: QKV epilogue -> q,k f16 [bh][t][64] (q*0.125*log2e),
//        v bf16 transposed+kv-permuted [bh][d][2048]
// EPI 1: fp32 write to outp
template <int EPI>
__global__ __launch_bounds__(512, 2) void gemm_nt(
    const u16* __restrict__ Ah, const u16* __restrict__ Bh, int K,
    u16* __restrict__ qg, u16* __restrict__ kg, u16* __restrict__ vtg,
    float* __restrict__ outp, int ldout) {
  __shared__ __align__(16) char lds[2 * 2 * 32768];   // [buf][A|B], 256x64 f16 each
  const int tid = threadIdx.x, lane = tid & 63, w = tid >> 6;
  const int g = lane >> 4, c16 = lane & 15;
  const int wr = w >> 2, wc = w & 3;      // 2 x 4 wave grid
  // XCD-chunked block swizzle (T1): nwg % 8 == 0 for both uses
  const int nwg = gridDim.x * gridDim.y;
  const int id = blockIdx.y * gridDim.x + blockIdx.x;
  const int sw = (id & 7) * (nwg >> 3) + (id >> 3);
  const int m0 = (sw / gridDim.x) * 256, n0 = (sw % gridDim.x) * 256;
  f32x4 acc[8][4] = {};

  // stage one K-step's A+B tiles (each 256x64 f16 = 32KB) into buffer `cur`
  auto STAGE = [&](int cur, int k0) {
#pragma unroll
    for (int tile = 0; tile < 2; tile++) {
      const u16* src = (tile == 0) ? Ah : Bh;
      const int row0 = (tile == 0) ? m0 : n0;
      char* dst = lds + cur * 65536 + tile * 32768;
#pragma unroll
      for (int i = 0; i < 4; i++) {
        int c = tid + 512 * i;
        int r = c >> 3;
        int sp = (c & 7) ^ (r & 7);
        gload_lds16(src + (size_t)(row0 + r) * K + k0 + sp * 8,
                    dst + w * 1024 + i * 8192);
      }
    }
  };

  const int NKT = K >> 6;
  STAGE(0, 0);
  __syncthreads();                       // drains vmcnt(0): buf0 ready
  for (int t = 0; t < NKT; t++) {
    const int cur = t & 1;
    if (t + 1 < NKT) STAGE(cur ^ 1, (t + 1) << 6);   // prefetch under compute
    const char* LA = lds + cur * 65536;
    const char* LB = lds + cur * 65536 + 32768;
#pragma unroll
    for (int ks = 0; ks < 2; ks++) {
      const int kb = ks * 64 + g * 16;
      short8 aF[8], bF[4];
#pragma unroll
      for (int mf = 0; mf < 8; mf++)
        aF[mf] = *(const short8*)(LA + swz(wr * 128 + mf * 16 + c16, kb));
#pragma unroll
      for (int nf = 0; nf < 4; nf++)
        bF[nf] = *(const short8*)(LB + swz(wc * 64 + nf * 16 + c16, kb));
#pragma unroll
      for (int mf = 0; mf < 8; mf++)
#pragma unroll
        for (int nf = 0; nf < 4; nf++)
          acc[mf][nf] = mfma16f(aF[mf], bF[nf], acc[mf][nf]);
    }
    __syncthreads();                     // all reads of buf[cur] done; next buf ready
  }

#pragma unroll
  for (int mf = 0; mf < 8; mf++)
#pragma unroll
    for (int nf = 0; nf < 4; nf++) {
      if (EPI == 0) {
        int col = n0 + wc * 64 + nf * 16 + c16;
        int p = (col >= 2 * C_EMB) ? 2 : (col >= C_EMB ? 1 : 0);
        int rem = col - p * C_EMB;
        int h = rem >> 6, d = rem & 63;
        int rowb = m0 + wr * 128 + mf * 16 + g * 4;
        int b = rowb >> 11, t0 = rowb & (T_SEQ - 1);
        int bhh = b * N_HD + h;
        if (p == 2) {
          ushort4 V4;
#pragma unroll
          for (int jj = 0; jj < 4; jj++) (&V4.x)[jj] = f2bf(acc[mf][nf][jj]);
          // kv permutation: swap bits 2<->3 of t within 16-groups so fa's PV
          // fragment (slot 2kk+hi) is one contiguous b128.
          int t0p = (t0 & ~12) | ((t0 & 4) << 1) | ((t0 & 8) >> 1);
          *(ushort4*)(vtg + ((size_t)bhh * D_HD + d) * T_SEQ + t0p) = V4;
        } else {
          u16* dst = (p == 0) ? qg : kg;
          // Q carries 1/sqrt(64) * log2(e) so scores are in exp2 domain
          float scl = (p == 0) ? 0.18033688f : 1.0f;
#pragma unroll
          for (int jj = 0; jj < 4; jj++)
            dst[((size_t)bhh * T_SEQ + t0 + jj) * D_HD + d] = f2h(acc[mf][nf][jj] * scl);
        }
      } else {
#pragma unroll
        for (int jj = 0; jj < 4; jj++) {
          int row = m0 + wr * 128 + mf * 16 + g * 4 + jj;
          int col = n0 + wc * 64 + nf * 16 + c16;
          outp[(size_t)row * ldout + col] = acc[mf][nf][jj];
        }
      }
    }
}

// ---------------- flash attention: swapped QK^T (f16), PV (bf16), fixed-offset exp2 ----
// grid (48 bh, 16 qb): all q-blocks of one head land on one XCD (48 % 8 == 0).
// P = 2^s directly (scores bounded, softmax offset-invariant, bf16/f32
// scale-invariant) -> no running max, no rescale. P spans ~2^±30 so P/V stay
// bf16 (f16 would overflow); q/k are f16 for 8x less score-input noise.
__global__ __launch_bounds__(256, 3) void fa_kernel(
    const u16* __restrict__ qg, const u16* __restrict__ kg,
    const u16* __restrict__ vtg, u16* __restrict__ yf) {
  __shared__ __align__(16) char lds[32768];   // K[128][64] swz | V^T[64][128] swz
  char* LK = lds;
  char* LV = lds + 16384;
  const int tid = threadIdx.x, lane = tid & 63, w = tid >> 6;
  const int r31 = lane & 31, hi = lane >> 5;
  const int bh = blockIdx.x, qb = blockIdx.y;
  const size_t kvbase = (size_t)bh * T_SEQ * D_HD;

  // Q B-frags (q pre-scaled by 0.125*log2e): row = qb*128 + w*32 + r31
  const u16* qrow = qg + kvbase + (size_t)(qb * 128 + w * 32 + r31) * D_HD + hi * 8;
  short8 qf[4];
#pragma unroll
  for (int ks = 0; ks < 4; ks++) qf[ks] = *(const short8*)(qrow + ks * 16);

  // precomputed LDS read addresses (XOR fields are bit-disjoint)
  const int eK = r31 & 7, eV = r31 & 15;
  const char* pK[4];
#pragma unroll
  for (int ks = 0; ks < 4; ks++)
    pK[ks] = LK + r31 * 128 + ((hi ^ (eK & 1)) << 4) + (((ks << 5) ^ ((eK >> 1) << 5)));
  const char* pV[2][8];
#pragma unroll
  for (int nd = 0; nd < 2; nd++)
#pragma unroll
    for (int kk = 0; kk < 8; kk++)
      pV[nd][kk] = LV + (nd * 32 + r31) * 256 + ((hi ^ (eV & 1)) << 4) +
                   (((kk << 5) ^ ((eV >> 1) << 5)));

  f32x16 yac[2] = {};
  f32x16 lacc = {};

  for (int kt = 0; kt < T_SEQ / 128; kt++) {
    const int kv0 = kt * 128;
    __syncthreads();
#pragma unroll
    for (int i = 0; i < 4; i++) {
      int c = tid + 256 * i;
      int kr = c >> 3, ksl = (c & 7) ^ (kr & 7);
      gload_lds16(kg + kvbase + (size_t)(kv0 + kr) * D_HD + ksl * 8,
                  LK + w * 1024 + i * 4096);
      int vd = c >> 4, vsl = (c & 15) ^ (vd & 15);
      gload_lds16(vtg + kvbase + (size_t)vd * T_SEQ + kv0 + vsl * 8,
                  LV + w * 1024 + i * 4096);
    }
    __syncthreads();

    // S^T = mfma(K, Q) in f16: rows kv, cols q; lane owns q = r31
    f32x16 p[4];
#pragma unroll
    for (int nb = 0; nb < 4; nb++) {
      f32x16 s = {};
#pragma unroll
      for (int ks = 0; ks < 4; ks++) {
        short8 kf = *(const short8*)(pK[ks] + nb * 4096);
        s = mfma32f(kf, qf[ks], s);
      }
      p[nb] = s;
    }

    // P = 2^S elementwise; accumulate sum vector-wise
#pragma unroll
    for (int nb = 0; nb < 4; nb++)
#pragma unroll
      for (int rr = 0; rr < 16; rr++) p[nb][rr] = EXP2(p[nb][rr]);
    lacc += (p[0] + p[1]) + (p[2] + p[3]);

    // PV (bf16): P frag = own-register packs; V frag = single b128 (kv-permuted)
#pragma unroll
    for (int nb = 0; nb < 4; nb++) {
      u32 wd[8];
#pragma unroll
      for (int i = 0; i < 8; i++)
        wd[i] = pack2bf(p[nb][2 * i], p[nb][2 * i + 1]);
#pragma unroll
      for (int q4 = 0; q4 < 2; q4++) {
        union { u32 u[4]; short8 s8; } pu;
        pu.u[0] = wd[q4 * 4 + 0]; pu.u[1] = wd[q4 * 4 + 1];
        pu.u[2] = wd[q4 * 4 + 2]; pu.u[3] = wd[q4 * 4 + 3];
        const int kk = nb * 2 + q4;
#pragma unroll
        for (int nd = 0; nd < 2; nd++) {
          short8 vf = *(const short8*)(pV[nd][kk]);
          yac[nd] = MFMA32B(vf, pu.s8, yac[nd]);
        }
      }
    }
  }

  // horizontal reduce of lacc, then combine the two kv-half partials
  float lsum;
  {
    float a = ((lacc[0] + lacc[1]) + (lacc[2] + lacc[3])) +
              ((lacc[4] + lacc[5]) + (lacc[6] + lacc[7]));
    float b = ((lacc[8] + lacc[9]) + (lacc[10] + lacc[11])) +
              ((lacc[12] + lacc[13]) + (lacc[14] + lacc[15]));
    lsum = a + b;
  }
  lsum += __shfl_xor(lsum, 32);
  float inv = 1.0f / lsum;
  const int b = bh / N_HD, hh = bh % N_HD;
  const int t = qb * 128 + w * 32 + r31;
  const size_t ybase = ((size_t)b * T_SEQ + t) * C_EMB + hh * D_HD;
#pragma unroll
  for (int nd = 0; nd < 2; nd++)
#pragma unroll
    for (int rq = 0; rq < 4; rq++) {
      int d0 = nd * 32 + rq * 8 + hi * 4;
      ushort4 H;
#pragma unroll
      for (int jj = 0; jj < 4; jj++)
        (&H.x)[jj] = f2h(yac[nd][rq * 4 + jj] * inv);
      *(ushort4*)(yf + ybase + d0) = H;
    }
}

// ---------------- launch ----------------
extern "C" void kernel_launch(void* const* d_in, const int* in_sizes, int n_in,
                              void* d_out, int out_size, void* d_ws, size_t ws_size,
                              hipStream_t stream) {
  (void)in_sizes; (void)n_in; (void)out_size;
  const float* x      = (const float*)d_in[0];
  const float* w_attn = (const float*)d_in[1];
  const float* w_proj = (const float*)d_in[2];
  float* out = (float*)d_out;

  const size_t NX  = (size_t)4 * T_SEQ * C_EMB;     // 6,291,456
  const size_t NWA = (size_t)3 * C_EMB * C_EMB;
  const size_t NWP = (size_t)C_EMB * C_EMB;
  const size_t NQ  = (size_t)N_BH * T_SEQ * D_HD;

  u16* ws = (u16*)d_ws;
  size_t off = 0;
  u16* XF  = ws + off; off += NX;    // f16
  u16* WAF = ws + off; off += NWA;   // f16
  u16* WPF = ws + off; off += NWP;   // f16
  u16* QF  = ws + off; off += NQ;    // f16
  u16* KF  = ws + off; off += NQ;    // f16
  u16* VT  = ws + off; off += NQ;    // bf16
  u16* YF  = ws + off; off += NX;    // f16
  if (ws_size < off * sizeof(u16)) return;

  {
    int n0 = (int)(NX / 4), n1 = (int)(NWA / 4), n2 = (int)(NWP / 4);
    size_t b = ((size_t)(n0 + n1 + n2) + 255) / 256;
    unsigned nb = (unsigned)(b > 2048 ? 2048 : b);
    cvt3_f16<<<nb, 256, 0, stream>>>(x, w_attn, w_proj, XF, WAF, WPF, n0, n1, n2);
  }

  gemm_nt<0><<<dim3(3 * C_EMB / 256, 4 * T_SEQ / 256), 512, 0, stream>>>(
      XF, WAF, C_EMB, QF, KF, VT, nullptr, 0);

  fa_kernel<<<dim3(N_BH, T_SEQ / 128), 256, 0, stream>>>(QF, KF, VT, YF);

  gemm_nt<1><<<dim3(C_EMB / 256, 4 * T_SEQ / 256), 512, 0, stream>>>(
      YF, WPF, C_EMB, nullptr, nullptr, nullptr, out, C_EMB);
}